// Round 6
// baseline (1829.885 us; speedup 1.0000x reference)
//
#include <hip/hip_runtime.h>

#define T_STEPS 512
#define INPUT   13
#define HIDDEN  64
#define NGATES  256   // 4*HIDDEN
#define MB      4     // batch rows per block: grid 1024 -> 4 blocks/CU
#define CS      16    // timesteps per x-chunk
#define XPAD    16    // padded input dim (13 -> 16)
#define NCHUNK  (T_STEPS / CS)
#define NTHREADS 512  // 128 gate-pairs x 4 quarter-columns

__device__ __forceinline__ float sigmoid_f(float x) {
    return 1.0f / (1.0f + __expf(-x));
}
__device__ __forceinline__ float tanh_f(float x) {
    // tanh(x) = 1 - 2/(1+exp(2x)); saturates correctly for large |x|
    return 1.0f - 2.0f / (1.0f + __expf(2.0f * x));
}

// Round-6: GATE-TILED layout to cut LDS read issue (the one per-CU
// invariant across rounds 0-5, all of which were perf-identical).
// Thread (gp, q): gp = tid>>2 owns gates {2gp, 2gp+1}; q = tid&3 owns
// h-columns q*16..q*16+15 and x-columns q*4..q*4+3.
//   - each ds_read_b128 of h feeds 8 FMAs (2 gates) instead of 4
//   - per-thread h-reads: 64 -> 16 b128 per step; per-CU LDS issue ~1.8x lower
//   - weights: 2x16 wh + 2x4 wi = 40 regs -> fits the empirical 64-VGPR
//     allocator ceiling (4-gate variants need 80 and would stream)
// Quad partial sums combine with 2 DPP shfl_xor per acc (VALU, no LDS).
// 512-thr blocks, 13.3 KB LDS -> 4 blocks/CU, 32 waves/CU.
__global__ __launch_bounds__(NTHREADS)
void lstm_fused_kernel(const float* __restrict__ x,
                       const float* __restrict__ W_ih,
                       const float* __restrict__ W_hh,
                       const float* __restrict__ b_ih,
                       const float* __restrict__ b_hh,
                       const float* __restrict__ W_fc,
                       const float* __restrict__ b_fc,
                       float* __restrict__ out)
{
    __shared__ float xs[2][MB][CS][XPAD];   // 8 KB: double-buffered x chunks
    __shared__ float hl[MB][HIDDEN];        // 1 KB: hidden state
    __shared__ float gl[MB][NGATES];        // 4 KB: gate pre-activations

    const int tid = threadIdx.x;
    const int q   = tid & 3;                // quarter-column index
    const int gp  = tid >> 2;               // gate-pair 0..127
    const int g0  = 2 * gp;                 // first owned gate
    const int row0 = blockIdx.x * MB;

    // ---- per-thread weights: 2 gates x quarter of the columns ----
    float wh[2][16];
    #pragma unroll
    for (int g = 0; g < 2; ++g)
        #pragma unroll
        for (int j = 0; j < 16; ++j)
            wh[g][j] = W_hh[(g0 + g) * HIDDEN + q * 16 + j];

    float wi[2][4];
    #pragma unroll
    for (int g = 0; g < 2; ++g)
        #pragma unroll
        for (int i = 0; i < 4; ++i) {
            const int idx = q * 4 + i;      // 0..15 (13..15 pad)
            wi[g][i] = (idx < INPUT) ? W_ih[(g0 + g) * INPUT + idx] : 0.0f;
        }

    // bias only on q==0 so the quad-sum counts it once
    float bias[2];
    #pragma unroll
    for (int g = 0; g < 2; ++g)
        bias[g] = (q == 0) ? (b_ih[g0 + g] + b_hh[g0 + g]) : 0.0f;

    // ---- init h (LDS) and c (regs, threads 0..255 own cell (r,k)) ----
    if (tid < MB * HIDDEN)
        hl[tid >> 6][tid & 63] = 0.0f;
    float c0 = 0.0f;

    // ---- x chunk loader: [MB][CS][XPAD] = 1024 floats, 2 elems/thread ----
    float stg[2];
    auto load_chunk = [&](int c) {
        #pragma unroll
        for (int k = 0; k < 2; ++k) {
            int idx = tid + k * NTHREADS;   // 0..1023
            int r   = idx >> 8;             // /(CS*XPAD)
            int rem = idx & 255;
            int tt  = rem >> 4;
            int i   = rem & 15;
            float v = 0.0f;
            if (i < INPUT)
                v = x[(size_t)(row0 + r) * (T_STEPS * INPUT)
                      + (size_t)(c * CS + tt) * INPUT + i];
            stg[k] = v;
        }
    };
    auto store_chunk = [&](int buf) {
        #pragma unroll
        for (int k = 0; k < 2; ++k) {
            int idx = tid + k * NTHREADS;
            ((float*)xs[buf])[idx] = stg[k];
        }
    };

    load_chunk(0);
    store_chunk(0);
    __syncthreads();

    for (int cidx = 0; cidx < NCHUNK; ++cidx) {
        const int cur = cidx & 1;
        if (cidx + 1 < NCHUNK)
            load_chunk(cidx + 1);   // issue early; consumed after step loop

        #pragma unroll 1
        for (int tt = 0; tt < CS; ++tt) {
            // ---- partial gates: acc[g][r] over this thread's 16+4 columns ----
            float acc[2][MB];
            #pragma unroll
            for (int g = 0; g < 2; ++g)
                #pragma unroll
                for (int r = 0; r < MB; ++r)
                    acc[g][r] = bias[g];

            // x part: 1 b128 per row, feeds 8 FMAs
            #pragma unroll
            for (int r = 0; r < MB; ++r) {
                const float4 xv = *(const float4*)&xs[cur][r][tt][q * 4];
                #pragma unroll
                for (int g = 0; g < 2; ++g) {
                    acc[g][r] = fmaf(xv.x, wi[g][0], acc[g][r]);
                    acc[g][r] = fmaf(xv.y, wi[g][1], acc[g][r]);
                    acc[g][r] = fmaf(xv.z, wi[g][2], acc[g][r]);
                    acc[g][r] = fmaf(xv.w, wi[g][3], acc[g][r]);
                }
            }

            // h part: 16 b128 per step, each feeds 8 FMAs
            #pragma unroll
            for (int j4 = 0; j4 < 4; ++j4) {
                #pragma unroll
                for (int r = 0; r < MB; ++r) {
                    const float4 hv = *(const float4*)&hl[r][q * 16 + j4 * 4];
                    #pragma unroll
                    for (int g = 0; g < 2; ++g) {
                        acc[g][r] = fmaf(hv.x, wh[g][j4 * 4 + 0], acc[g][r]);
                        acc[g][r] = fmaf(hv.y, wh[g][j4 * 4 + 1], acc[g][r]);
                        acc[g][r] = fmaf(hv.z, wh[g][j4 * 4 + 2], acc[g][r]);
                        acc[g][r] = fmaf(hv.w, wh[g][j4 * 4 + 3], acc[g][r]);
                    }
                }
            }

            // ---- quad reduction (lanes gp*4 .. gp*4+3): DPP, stays on VALU ----
            #pragma unroll
            for (int g = 0; g < 2; ++g)
                #pragma unroll
                for (int r = 0; r < MB; ++r) {
                    acc[g][r] += __shfl_xor(acc[g][r], 1);
                    acc[g][r] += __shfl_xor(acc[g][r], 2);
                }

            // q==0 lane of each quad writes both gates' pre-activations
            if (q == 0) {
                #pragma unroll
                for (int r = 0; r < MB; ++r) {
                    float2 v = make_float2(acc[0][r], acc[1][r]);
                    *(float2*)&gl[r][g0] = v;
                }
            }
            __syncthreads();

            // ---- cell update: threads 0..255 own cell (r = tid>>6, k = tid&63) ----
            if (tid < MB * HIDDEN) {
                const int k = tid & 63;
                const int r = tid >> 6;          // 0..3
                float ig = sigmoid_f(gl[r][k]);
                float fg = sigmoid_f(gl[r][64 + k]);
                float gg = tanh_f   (gl[r][128 + k]);
                float og = sigmoid_f(gl[r][192 + k]);
                c0 = fg * c0 + ig * gg;
                hl[r][k] = og * tanh_f(c0);
            }
            __syncthreads();
        }

        if (cidx + 1 < NCHUNK) {
            store_chunk(1 - cur);   // waits on the global loads issued above
            __syncthreads();
        }
    }

    // ---- epilogue: out[row] = sigmoid(h_T . W_fc + b_fc) ----
    if (tid < MB) {
        float acc = b_fc[0];
        #pragma unroll
        for (int j = 0; j < HIDDEN; ++j)
            acc = fmaf(hl[tid][j], W_fc[j], acc);
        out[row0 + tid] = sigmoid_f(acc);
    }
}

extern "C" void kernel_launch(void* const* d_in, const int* in_sizes, int n_in,
                              void* d_out, int out_size, void* d_ws, size_t ws_size,
                              hipStream_t stream) {
    const float* x    = (const float*)d_in[0];
    const float* W_ih = (const float*)d_in[1];
    const float* W_hh = (const float*)d_in[2];
    const float* b_ih = (const float*)d_in[3];
    const float* b_hh = (const float*)d_in[4];
    const float* W_fc = (const float*)d_in[5];
    const float* b_fc = (const float*)d_in[6];
    float* out = (float*)d_out;

    const int B = 4096;
    dim3 grid(B / MB), block(NTHREADS);
    lstm_fused_kernel<<<grid, block, 0, stream>>>(x, W_ih, W_hh, b_ih, b_hh,
                                                  W_fc, b_fc, out);
}

// Round 7
// 631.855 us; speedup vs baseline: 2.8961x; 2.8961x over previous
//
#include <hip/hip_runtime.h>

#define T_STEPS 512
#define INPUT   13
#define HIDDEN  64
#define MB      16    // batch rows per block = full MFMA M-tile
#define CS      8     // timesteps per x-chunk
#define NCHUNK  (T_STEPS / CS)

typedef __attribute__((ext_vector_type(8))) short bf16x8;  // MFMA A/B frag (4 VGPR)
typedef __attribute__((ext_vector_type(4))) float f32x4;   // MFMA C/D frag

__device__ __forceinline__ float sigmoid_f(float x) {
    return 1.0f / (1.0f + __expf(-x));
}
__device__ __forceinline__ float tanh_f(float x) {
    return 1.0f - 2.0f / (1.0f + __expf(2.0f * x));
}
// float -> bf16 round-to-nearest-even (values are finite; no NaN handling)
__device__ __forceinline__ unsigned short f2bf(float f) {
    unsigned u = __float_as_uint(f);
    return (unsigned short)((u + 0x7FFFu + ((u >> 16) & 1u)) >> 16);
}
__device__ __forceinline__ float bf2f(unsigned short h) {
    return __uint_as_float(((unsigned)h) << 16);
}

// Rounds 0-6 post-mortem: every scalar-FMA layout issues ~1360 LDS instrs
// per CU per step (h/x broadcasts; shuffles are ds_bpermute = LDS too) and
// all run at the same ~7.6k cyc/step/CU = LDS-pipe issue wall. Escape =
// MFMA with 3-term bf16 split (hi*hi + hi*lo + lo*hi; bf16 products are
// exact in the f32 accumulator -> ~1e-5 relative error, fp32-safe).
// Layout: 1 block/CU, 4 waves; wave w owns N-tiles {w,w+4,w+8,w+12} =
// gates i,f,g,o of cells 16w..16w+15 -> cell update fully in-register.
// Weights resident as 24 B-frags (96 VGPR). h goes through 4KB swizzled
// LDS as bf16 hi/lo. LDS issues/CU/step: ~1360 -> ~70.
__global__ __launch_bounds__(256, 1)
void lstm_mfma_kernel(const float* __restrict__ x,
                      const float* __restrict__ W_ih,
                      const float* __restrict__ W_hh,
                      const float* __restrict__ b_ih,
                      const float* __restrict__ b_hh,
                      const float* __restrict__ W_fc,
                      const float* __restrict__ b_fc,
                      float* __restrict__ out)
{
    // h fragments: [split][row][k'] bf16, XOR-swizzled (slot ^= row&7) so the
    // A-frag b128 reads (16 lanes = 16 rows at stride 128B) are 2-way max.
    __shared__ unsigned short hA[2][MB][HIDDEN];            // 4 KB
    // x fragments: [buf][split][tt][row][k'(32, zero-padded)], slot ^= row&3
    __shared__ unsigned short xA[2][2][CS][MB][32];         // 32 KB
    __shared__ float hf[MB][HIDDEN];                        // epilogue, 4 KB

    const int tid = threadIdx.x;
    const int w   = tid >> 6;      // wave 0..3
    const int l   = tid & 63;
    const int lr  = l & 15;        // MFMA row/col index
    const int lg  = l >> 4;        // MFMA k-group
    const int row0 = blockIdx.x * MB;

    // ---- resident weight B-frags, built once ----
    // Wcat[g][k]: k<64 -> W_hh[g][k]; 64<=k<77 -> W_ih[g][k-64]; else 0.
    // B-frag element j of (tile, kf): B[k = kf*32 + lg*8 + j][col = lr],
    // col maps to gate = 64*gt + 16*w + lr  (tile index gt*4 + w).
    bf16x8 Bf[4][3][2];
    float  bias[4];
    #pragma unroll
    for (int gt = 0; gt < 4; ++gt) {
        const int gate = gt * 64 + 16 * w + lr;
        bias[gt] = b_ih[gate] + b_hh[gate];
        #pragma unroll
        for (int kf = 0; kf < 3; ++kf) {
            bf16x8 bh, bl;
            #pragma unroll
            for (int j = 0; j < 8; ++j) {
                const int k = kf * 32 + lg * 8 + j;
                float v = 0.0f;
                if (k < 64)      v = W_hh[gate * HIDDEN + k];
                else if (k < 77) v = W_ih[gate * INPUT + (k - 64)];
                const unsigned short hi = f2bf(v);
                const unsigned short lo = f2bf(v - bf2f(hi));
                bh[j] = (short)hi;
                bl[j] = (short)lo;
            }
            Bf[gt][kf][0] = bh;
            Bf[gt][kf][1] = bl;
        }
    }

    // ---- zero LDS (h0 = 0; x pad lanes k>=16 stay 0 forever) ----
    for (int i = tid; i < 2 * MB * HIDDEN; i += 256)
        ((unsigned short*)hA)[i] = 0;
    for (int i = tid; i < 2 * 2 * CS * MB * 32; i += 256)
        ((unsigned short*)xA)[i] = 0;

    float c[4]    = {0.f, 0.f, 0.f, 0.f};
    float hreg[4] = {0.f, 0.f, 0.f, 0.f};

    // ---- x chunk loader: 16 rows x CS tt x 16 (padded) = 2048 slots ----
    float stg[8];
    auto load_chunk = [&](int ch) {
        #pragma unroll
        for (int s = 0; s < 8; ++s) {
            const int idx = tid + s * 256;   // 0..2047
            const int i   = idx & 15;
            const int tt  = (idx >> 4) & 7;
            const int r   = idx >> 7;        // 0..15
            float v = 0.0f;
            if (i < INPUT)
                v = x[(size_t)(row0 + r) * (T_STEPS * INPUT)
                      + (size_t)(ch * CS + tt) * INPUT + i];
            stg[s] = v;
        }
    };
    auto store_chunk = [&](int buf) {
        #pragma unroll
        for (int s = 0; s < 8; ++s) {
            const int idx = tid + s * 256;
            const int i   = idx & 15;
            const int tt  = (idx >> 4) & 7;
            const int r   = idx >> 7;
            const unsigned short hi = f2bf(stg[s]);
            const unsigned short lo = f2bf(stg[s] - bf2f(hi));
            const int kp = (i & 7) | ((((i >> 3)) ^ (r & 3)) << 3);
            xA[buf][0][tt][r][kp] = hi;
            xA[buf][1][tt][r][kp] = lo;
        }
    };

    load_chunk(0);
    __syncthreads();          // zero-init visible to all
    store_chunk(0);
    __syncthreads();

    for (int ch = 0; ch < NCHUNK; ++ch) {
        const int cur = ch & 1;
        if (ch + 1 < NCHUNK)
            load_chunk(ch + 1);          // global loads in flight over 8 steps

        #pragma unroll 1
        for (int tt = 0; tt < CS; ++tt) {
            // ---- A-frag reads: row = lr, 8 consecutive k at slot lg (swz) ----
            bf16x8 ah[2][2];   // [split][kf]
            #pragma unroll
            for (int sp = 0; sp < 2; ++sp)
                #pragma unroll
                for (int kf = 0; kf < 2; ++kf) {
                    const int slot = (kf * 4 + lg) ^ (lr & 7);
                    ah[sp][kf] = *(const bf16x8*)((const char*)&hA[sp][lr][0] + slot * 16);
                }
            bf16x8 ax[2];
            #pragma unroll
            for (int sp = 0; sp < 2; ++sp) {
                const int slot = lg ^ (lr & 3);
                ax[sp] = *(const bf16x8*)((const char*)&xA[cur][sp][tt][lr][0] + slot * 16);
            }
            __syncthreads();   // reads done before anyone overwrites hA

            // ---- gate GEMM: 9 MFMAs per gate-type (3 kf x {hh, hl, lh}) ----
            f32x4 acc[4];
            #pragma unroll
            for (int gt = 0; gt < 4; ++gt) {
                f32x4 a = {bias[gt], bias[gt], bias[gt], bias[gt]};
                #pragma unroll
                for (int kf = 0; kf < 2; ++kf) {
                    a = __builtin_amdgcn_mfma_f32_16x16x32_bf16(ah[0][kf], Bf[gt][kf][0], a, 0, 0, 0);
                    a = __builtin_amdgcn_mfma_f32_16x16x32_bf16(ah[0][kf], Bf[gt][kf][1], a, 0, 0, 0);
                    a = __builtin_amdgcn_mfma_f32_16x16x32_bf16(ah[1][kf], Bf[gt][kf][0], a, 0, 0, 0);
                }
                a = __builtin_amdgcn_mfma_f32_16x16x32_bf16(ax[0], Bf[gt][2][0], a, 0, 0, 0);
                a = __builtin_amdgcn_mfma_f32_16x16x32_bf16(ax[0], Bf[gt][2][1], a, 0, 0, 0);
                a = __builtin_amdgcn_mfma_f32_16x16x32_bf16(ax[1], Bf[gt][2][0], a, 0, 0, 0);
                acc[gt] = a;
            }

            // ---- in-register cell update; write split h to LDS ----
            // D layout: row = lg*4 + r, col(cell) = 16w + lr
            #pragma unroll
            for (int r = 0; r < 4; ++r) {
                const float ig = sigmoid_f(acc[0][r]);
                const float fg = sigmoid_f(acc[1][r]);
                const float gg = tanh_f   (acc[2][r]);
                const float og = sigmoid_f(acc[3][r]);
                c[r] = fg * c[r] + ig * gg;
                const float h = og * tanh_f(c[r]);
                hreg[r] = h;
                const unsigned short hi = f2bf(h);
                const unsigned short lo = f2bf(h - bf2f(hi));
                const int row = lg * 4 + r;
                const int k   = 16 * w + lr;
                const int kp  = (k & 7) | ((((k >> 3)) ^ (row & 7)) << 3);
                hA[0][row][kp] = hi;
                hA[1][row][kp] = lo;
            }
            __syncthreads();   // h_t complete before next step's reads
        }

        if (ch + 1 < NCHUNK) {
            store_chunk(1 - cur);        // waits on the global loads above
            __syncthreads();
        }
    }

    // ---- epilogue: out[row] = sigmoid(h_T . W_fc + b_fc) ----
    #pragma unroll
    for (int r = 0; r < 4; ++r)
        hf[lg * 4 + r][16 * w + lr] = hreg[r];
    __syncthreads();
    if (tid < MB) {
        float a = b_fc[0];
        #pragma unroll
        for (int j = 0; j < HIDDEN; ++j)
            a = fmaf(hf[tid][j], W_fc[j], a);
        out[row0 + tid] = sigmoid_f(a);
    }
}

extern "C" void kernel_launch(void* const* d_in, const int* in_sizes, int n_in,
                              void* d_out, int out_size, void* d_ws, size_t ws_size,
                              hipStream_t stream) {
    const float* x    = (const float*)d_in[0];
    const float* W_ih = (const float*)d_in[1];
    const float* W_hh = (const float*)d_in[2];
    const float* b_ih = (const float*)d_in[3];
    const float* b_hh = (const float*)d_in[4];
    const float* W_fc = (const float*)d_in[5];
    const float* b_fc = (const float*)d_in[6];
    float* out = (float*)d_out;

    const int B = 4096;
    dim3 grid(B / MB), block(256);
    lstm_mfma_kernel<<<grid, block, 0, stream>>>(x, W_ih, W_hh, b_ih, b_hh,
                                                 W_fc, b_fc, out);
}